// Round 11
// baseline (513.432 us; speedup 1.0000x reference)
//
#include <hip/hip_runtime.h>
#include <hip/hip_fp16.h>
#include <math.h>

#define NN 50000
#define NE 800000
#define DD 128
#define NG 64
#define NEG 0.2f
#define KMAX 64                  // fixed-width adjacency slots per node
#define OCAP 65536               // overflow pair capacity (never hit: deg<=~40)
#define NBUK 391                 // dst buckets of 128 nodes
#define BCAP 3072                // bin capacity (mean 2048, 23-sigma headroom)
#define MM_BLOCKS 391            // ceil(50000/128)
#define SC_BLOCKS 782            // NE/4/256

typedef _Float16 half8 __attribute__((ext_vector_type(8)));
typedef float f32x4 __attribute__((ext_vector_type(4)));

__device__ __forceinline__ float leaky(float x) { return x >= 0.f ? x : NEG * x; }

__device__ __forceinline__ float wave_sum(float v) {
    #pragma unroll
    for (int o = 32; o; o >>= 1) v += __shfl_xor(v, o, 64);
    return v;
}

// ---------------- W prep: transpose + fp16 cast, Wt[col][k] ----------------
__launch_bounds__(256)
__global__ void k_wprep(const float* __restrict__ W1, const float* __restrict__ W2,
                        __half* __restrict__ Wt1, __half* __restrict__ Wt2) {
    int blk = blockIdx.x;                  // 0..7: 4 per W
    const float* W = (blk < 4) ? W1 : W2;
    __half* Wt = (blk < 4) ? Wt1 : Wt2;
    int t = threadIdx.x;
    int col = (blk & 3) * 32 + (t & 31);
    int kh = t >> 5;                       // 0..7
    #pragma unroll
    for (int kk = 0; kk < 16; kk++) {
        int k = kh * 16 + kk;
        Wt[col * DD + k] = __float2half(W[k * DD + col]);
    }
}

// ---------------- MFMA fp16 GEMM body ----------------
// 128 rows/block, 4 waves x (32 rows x 128 cols). mfma_f32_16x16x32_f16.
// Per-16x16-tile verified mappings: D row=(l>>4)*4+r, col=l&15 (m89);
// k-fragments use contiguous-8 ordering — valid for ANY true HW k-order since
// A and B share the same (symmetric) k map and Sum_k is permutation-invariant.
// LDS 16B-XOR swizzle (byte ^= (row&7)<<4) kills the 16-way row-stride conflict.
template<bool SRC16>
__device__ __forceinline__ void mm_body(
        int gblk, const void* __restrict__ Xsrc, const __half* __restrict__ Wt,
        const float* __restrict__ att_s, const float* __restrict__ att_d,
        __half* __restrict__ Hh, float* __restrict__ asrc, float* __restrict__ adst) {
    __shared__ __align__(16) unsigned char XsB[128 * 256];   // 32 KB
    __shared__ __align__(16) unsigned char WtB[128 * 256];   // 32 KB
    int tid = threadIdx.x;
    int rowbase = gblk * 128;
    #pragma unroll
    for (int i = 0; i < 8; i++) {                  // stage A tile (fp16, swizzled)
        int slot = tid + i * 256;
        int rl = slot >> 4, c16 = slot & 15;
        int gr = rowbase + rl; if (gr > NN - 1) gr = NN - 1;
        uint4 v;
        if constexpr (SRC16) {
            v = ((const uint4*)Xsrc)[gr * 16 + c16];
        } else {
            const float4* Xf = (const float4*)Xsrc;
            float4 f0 = Xf[(size_t)gr * 32 + c16 * 2];
            float4 f1 = Xf[(size_t)gr * 32 + c16 * 2 + 1];
            __half2* o = (__half2*)&v;
            o[0] = __floats2half2_rn(f0.x, f0.y);
            o[1] = __floats2half2_rn(f0.z, f0.w);
            o[2] = __floats2half2_rn(f1.x, f1.y);
            o[3] = __floats2half2_rn(f1.z, f1.w);
        }
        *(uint4*)(XsB + rl * 256 + ((c16 * 16) ^ ((rl & 7) << 4))) = v;
    }
    #pragma unroll
    for (int i = 0; i < 8; i++) {                  // stage Wt (swizzled)
        int slot = tid + i * 256;
        int col = slot >> 4, c16 = slot & 15;
        uint4 v = ((const uint4*)Wt)[col * 16 + c16];
        *(uint4*)(WtB + col * 256 + ((c16 * 16) ^ ((col & 7) << 4))) = v;
    }
    __syncthreads();

    int l = tid & 63, wv = tid >> 6;
    f32x4 acc0[8], acc1[8];
    #pragma unroll
    for (int n = 0; n < 8; n++) { acc0[n] = (f32x4){0.f,0.f,0.f,0.f}; acc1[n] = (f32x4){0.f,0.f,0.f,0.f}; }
    int row0 = wv * 32 + (l & 15);
    int row1 = row0 + 16;
    int sw = (l & 7) << 4;                         // == (row&7)<<4 == (col&7)<<4
    #pragma unroll
    for (int ks = 0; ks < 4; ks++) {
        int kb = ks * 64 + ((l >> 4) << 4);        // byte offset of this lane's 8 fp16
        half8 a0 = *(const half8*)(XsB + row0 * 256 + (kb ^ sw));
        half8 a1 = *(const half8*)(XsB + row1 * 256 + (kb ^ sw));
        #pragma unroll
        for (int n = 0; n < 8; n++) {
            int col = n * 16 + (l & 15);
            half8 b = *(const half8*)(WtB + col * 256 + (kb ^ sw));
            acc0[n] = __builtin_amdgcn_mfma_f32_16x16x32_f16(a0, b, acc0[n], 0, 0, 0);
            acc1[n] = __builtin_amdgcn_mfma_f32_16x16x32_f16(a1, b, acc1[n], 0, 0, 0);
        }
    }
    // epilogue: attention dots from f32 acc (row-reduce over the 16 col-lanes)
    float asv[8], adv[8];
    #pragma unroll
    for (int n = 0; n < 8; n++) {
        asv[n] = att_s[n * 16 + (l & 15)];
        adv[n] = att_d[n * 16 + (l & 15)];
    }
    #pragma unroll
    for (int a = 0; a < 2; a++) {
        #pragma unroll
        for (int r = 0; r < 4; r++) {
            float ps = 0.f, pd = 0.f;
            #pragma unroll
            for (int n = 0; n < 8; n++) {
                float c = a ? acc1[n][r] : acc0[n][r];
                ps = fmaf(c, asv[n], ps);
                pd = fmaf(c, adv[n], pd);
            }
            #pragma unroll
            for (int off = 1; off < 16; off <<= 1) {
                ps += __shfl_xor(ps, off, 64);
                pd += __shfl_xor(pd, off, 64);
            }
            int gr = rowbase + wv * 32 + a * 16 + ((l >> 4) << 2) + r;
            if ((l & 15) == 0 && gr < NN) { asrc[gr] = ps; adst[gr] = pd; }
        }
    }
    // bounce acc -> LDS (linear fp16 [row][col]) -> coalesced 16B global stores
    #pragma unroll
    for (int a = 0; a < 2; a++) {
        #pragma unroll
        for (int n = 0; n < 8; n++) {
            #pragma unroll
            for (int r = 0; r < 4; r++) {
                int rl = wv * 32 + a * 16 + ((l >> 4) << 2) + r;
                float c = a ? acc1[n][r] : acc0[n][r];
                *(__half*)(XsB + rl * 256 + (n * 16 + (l & 15)) * 2) = __float2half(c);
            }
        }
    }
    __syncthreads();
    #pragma unroll
    for (int i = 0; i < 8; i++) {
        int slot = i * 64 + l;
        int rl = wv * 32 + (slot >> 4), c16 = slot & 15;
        int gr = rowbase + rl;
        if (gr < NN)
            ((uint4*)Hh)[(size_t)gr * 16 + c16] = *(const uint4*)(XsB + rl * 256 + c16 * 16);
    }
}

// bin-scatter (pass 1 of build): merged writes into per-bucket bins
__device__ __forceinline__ void scat_body(
        int sblk, const int* __restrict__ src, const int* __restrict__ dst,
        int* __restrict__ bcnt, unsigned* __restrict__ bins,
        int2* __restrict__ opair, int* __restrict__ ocnt) {
    int e = sblk * 256 + threadIdx.x;              // group of 4 edges
    if (e < NE / 4) {
        int4 s4 = ((const int4*)src)[e];
        int4 d4 = ((const int4*)dst)[e];
        int ss[4] = {s4.x, s4.y, s4.z, s4.w};
        int dd[4] = {d4.x, d4.y, d4.z, d4.w};
        #pragma unroll
        for (int u = 0; u < 4; u++) {
            int s = ss[u], d = dd[u];
            int b = d >> 7;
            int slot = atomicAdd(&bcnt[b], 1);
            if (slot < BCAP) bins[b * BCAP + slot] = ((unsigned)d << 16) | (unsigned)s;
            else { int o = atomicAdd(ocnt, 1); if (o < OCAP) opair[o] = make_int2(s, d); }
        }
    }
}

// fused: layer-1 MFMA gemm (1/3 of blocks) || bin-scatter (2/3)
__launch_bounds__(256)
__global__ void k_mm1_sc(const float* __restrict__ X, const __half* __restrict__ Wt1,
                         const float* __restrict__ as1, const float* __restrict__ ad1,
                         __half* __restrict__ Hh, float* __restrict__ asrc,
                         float* __restrict__ adst,
                         const int* __restrict__ src, const int* __restrict__ dst,
                         int* __restrict__ bcnt, unsigned* __restrict__ bins,
                         int2* __restrict__ opair, int* __restrict__ ocnt) {
    int r = blockIdx.x % 3;
    if (r == 0)
        mm_body<false>(blockIdx.x / 3, X, Wt1, as1, ad1, Hh, asrc, adst);
    else
        scat_body((blockIdx.x / 3) * 2 + (r - 1), src, dst, bcnt, bins, opair, ocnt);
}

__launch_bounds__(256)
__global__ void k_mm2(const __half* __restrict__ Yh, const __half* __restrict__ Wt2,
                      const float* __restrict__ as2, const float* __restrict__ ad2,
                      __half* __restrict__ Hh, float* __restrict__ asrc,
                      float* __restrict__ adst) {
    mm_body<true>(blockIdx.x, Yh, Wt2, as2, ad2, Hh, asrc, adst);
}

// pass 2 of build: per-128-node bucket, adjacency assembled in LDS, written coalesced
__launch_bounds__(256)
__global__ void k_bbuild(const int* __restrict__ bcnt, const unsigned* __restrict__ bins,
                         unsigned short* __restrict__ adj, int* __restrict__ deg,
                         int2* __restrict__ opair, int* __restrict__ ocnt) {
    __shared__ unsigned short ladj[128 * KMAX];    // 16 KB
    __shared__ int ldeg[128];
    int tid = threadIdx.x, b = blockIdx.x;
    if (tid < 128) ldeg[tid] = 0;
    __syncthreads();
    int n = bcnt[b]; if (n > BCAP) n = BCAP;
    for (int i = tid; i < n; i += 256) {
        unsigned p = bins[b * BCAP + i];
        int s = (int)(p & 0xFFFFu);
        int dl = (int)((p >> 16) & 127u);
        int r = atomicAdd(&ldeg[dl], 1);
        if (r < KMAX) ladj[dl * KMAX + r] = (unsigned short)s;
        else { int o = atomicAdd(ocnt, 1); if (o < OCAP) opair[o] = make_int2(s, (int)(p >> 16)); }
    }
    __syncthreads();
    const uint4* lsrc = (const uint4*)ladj;
    uint4* gdst = (uint4*)adj;
    #pragma unroll
    for (int i = 0; i < 4; i++)                    // 16 KB coalesced
        gdst[b * 1024 + tid + i * 256] = lsrc[tid + i * 256];
    int base = b * 128;
    if (tid < 128 && base + tid < NN) deg[base + tid] = ldeg[tid];
}

// ---------------- per-dst softmax + weighted aggregation ----------------
// One wave per dst node. Adjacency (ushort) + self-loop cached in regs via one
// coalesced load; per-edge exp in regs; (src,coef) via __shfl. Quarter-wave
// gather: 16 lanes/row (uint4 = 8 fp16), 16 edges (4 KB) in flight.
// POOL: fused global_mean_pool via LDS + per-run atomics. !POOL: Y out fp16.
template<int WPB, bool POOL>
__launch_bounds__(WPB * 64)
__global__ void k_aggr(const __half* __restrict__ Hh, const float* __restrict__ asrc,
                       const float* __restrict__ adst, const int* __restrict__ degp,
                       const unsigned short* __restrict__ adj,
                       const int2* __restrict__ opairs, const int* __restrict__ ocnt,
                       const float* __restrict__ bias, const int* __restrict__ batch,
                       float* __restrict__ gsum, int* __restrict__ gcnt,
                       __half* __restrict__ Yh) {
    int tid = threadIdx.x;
    int lane = tid & 63;
    int h = lane >> 4;                 // quarter id: edge slot within group of 4
    int fl = lane & 15;                // feature lane (8 fp16 each)
    int w = tid >> 6;
    int v = blockIdx.x * WPB + w;      // grid sized exactly: v < NN always
    float adv = adst[v];
    float e_self = __expf(leaky(asrc[v] + adv));
    int deg = degp[v];
    bool self_in_reg = (deg < KMAX);
    int lim = self_in_reg ? deg + 1 : KMAX;   // reg-cached slots (incl. self)

    int   sarr = v;
    float evl  = 0.f;
    if (lane < lim) {
        sarr = (lane < deg) ? (int)adj[(v << 6) + lane] : v;
        evl  = (lane < deg) ? __expf(leaky(asrc[sarr] + adv)) : e_self;
    }
    int oc = 0;
    float sloc = evl;
    if (deg > KMAX) {                              // overflow (never in practice)
        oc = ocnt[0];
        if (oc > OCAP) oc = OCAP;
        for (int j = lane; j < oc; j += 64) {
            int2 p = opairs[j];
            if (p.y == v) sloc += __expf(leaky(asrc[p.x] + adv));
        }
    }
    float ssum = wave_sum(sloc) + (self_in_reg ? 0.f : e_self);
    float inv = 1.f / (ssum + 1e-16f);

    const uint4* H4 = (const uint4*)Hh;            // row = 16 uint4 (256 B)
    float acc[8];
    #pragma unroll
    for (int t = 0; t < 8; t++) acc[t] = 0.f;

    for (int j = 0; j < lim; j += 16) {            // 16 edges per batch
        int su[4]; float cu[4];
        #pragma unroll
        for (int u = 0; u < 4; u++) {
            int idx = j + 4 * u + h;
            int im  = idx & 63;
            int   s = __shfl(sarr, im, 64);
            float p = __shfl(evl,  im, 64);
            bool ok = idx < lim;
            su[u] = ok ? s : v;
            cu[u] = ok ? p * inv : 0.f;
        }
        uint4 hv[4];
        #pragma unroll
        for (int u = 0; u < 4; u++)
            hv[u] = H4[(size_t)su[u] * 16 + fl];   // 4 independent 1KB wave-loads
        #pragma unroll
        for (int u = 0; u < 4; u++) {
            const __half2* p2 = (const __half2*)&hv[u];
            #pragma unroll
            for (int t = 0; t < 4; t++) {
                float2 f = __half22float2(p2[t]);
                acc[2 * t]     = fmaf(cu[u], f.x, acc[2 * t]);
                acc[2 * t + 1] = fmaf(cu[u], f.y, acc[2 * t + 1]);
            }
        }
    }
    if (!self_in_reg) {                            // deferred self + overflow
        {
            float c0 = (h == 0) ? e_self * inv : 0.f;
            uint4 hv = H4[(size_t)v * 16 + fl];
            const __half2* p2 = (const __half2*)&hv;
            #pragma unroll
            for (int t = 0; t < 4; t++) {
                float2 f = __half22float2(p2[t]);
                acc[2 * t]     = fmaf(c0, f.x, acc[2 * t]);
                acc[2 * t + 1] = fmaf(c0, f.y, acc[2 * t + 1]);
            }
        }
        for (int j = 0; j < oc; ++j) {             // expected 0 iterations
            int2 p = opairs[j];
            if (p.y != v) continue;
            float c = (h == 0) ? __expf(leaky(asrc[p.x] + adv)) * inv : 0.f;
            uint4 hv = H4[(size_t)p.x * 16 + fl];
            const __half2* p2 = (const __half2*)&hv;
            #pragma unroll
            for (int t = 0; t < 4; t++) {
                float2 f = __half22float2(p2[t]);
                acc[2 * t]     = fmaf(c, f.x, acc[2 * t]);
                acc[2 * t + 1] = fmaf(c, f.y, acc[2 * t + 1]);
            }
        }
    }
    #pragma unroll
    for (int t = 0; t < 8; t++) {                  // combine the 4 quarters
        acc[t] += __shfl_xor(acc[t], 16, 64);
        acc[t] += __shfl_xor(acc[t], 32, 64);
    }
    if constexpr (POOL) {
        __shared__ float sh[WPB][DD];
        __shared__ int sb[WPB];
        if (lane < 16) {
            const float4* B4 = (const float4*)bias;
            float4 b0 = B4[2 * fl], b1 = B4[2 * fl + 1];
            float4 o0, o1;
            o0.x = fmaxf(acc[0] + b0.x, 0.f);
            o0.y = fmaxf(acc[1] + b0.y, 0.f);
            o0.z = fmaxf(acc[2] + b0.z, 0.f);
            o0.w = fmaxf(acc[3] + b0.w, 0.f);
            o1.x = fmaxf(acc[4] + b1.x, 0.f);
            o1.y = fmaxf(acc[5] + b1.y, 0.f);
            o1.z = fmaxf(acc[6] + b1.z, 0.f);
            o1.w = fmaxf(acc[7] + b1.w, 0.f);
            *(float4*)&sh[w][8 * fl]     = o0;
            *(float4*)&sh[w][8 * fl + 4] = o1;
        }
        if (lane == 0) sb[w] = batch[v];
        __syncthreads();
        if (tid < DD) {                            // per-feature run flush
            int f = tid;
            float a = 0.f; int run = 0; int bcur = sb[0];
            #pragma unroll
            for (int r = 0; r < WPB; r++) {
                int b = sb[r];
                if (b != bcur) {
                    atomicAdd(&gsum[bcur * DD + f], a);
                    if (f == 0) atomicAdd(&gcnt[bcur], run);
                    a = 0.f; run = 0; bcur = b;
                }
                a += sh[r][f]; run++;
            }
            atomicAdd(&gsum[bcur * DD + f], a);
            if (f == 0) atomicAdd(&gcnt[bcur], run);
        }
    } else {
        if (lane < 16) {
            const float4* B4 = (const float4*)bias;
            float4 b0 = B4[2 * fl], b1 = B4[2 * fl + 1];
            float o[8];
            o[0] = fmaxf(acc[0] + b0.x, 0.f);
            o[1] = fmaxf(acc[1] + b0.y, 0.f);
            o[2] = fmaxf(acc[2] + b0.z, 0.f);
            o[3] = fmaxf(acc[3] + b0.w, 0.f);
            o[4] = fmaxf(acc[4] + b1.x, 0.f);
            o[5] = fmaxf(acc[5] + b1.y, 0.f);
            o[6] = fmaxf(acc[6] + b1.z, 0.f);
            o[7] = fmaxf(acc[7] + b1.w, 0.f);
            uint4 pk;
            __half2* p2 = (__half2*)&pk;
            p2[0] = __floats2half2_rn(o[0], o[1]);
            p2[1] = __floats2half2_rn(o[2], o[3]);
            p2[2] = __floats2half2_rn(o[4], o[5]);
            p2[3] = __floats2half2_rn(o[6], o[7]);
            ((uint4*)Yh)[(size_t)v * 16 + fl] = pk;
        }
    }
}

// ---------------- final MLP: relu(g@W1+b1)@W2+b2 ----------------
__launch_bounds__(128)
__global__ void k_mlp(const float* __restrict__ gsum, const int* __restrict__ gcnt,
                      const float* __restrict__ W1, const float* __restrict__ b1,
                      const float* __restrict__ W2, const float* __restrict__ b2,
                      float* __restrict__ out) {
    __shared__ float g[DD];
    __shared__ float red[2];
    int gi = blockIdx.x, t = threadIdx.x;
    float cnt = fmaxf((float)gcnt[gi], 1.f);
    g[t] = gsum[gi * DD + t] / cnt;
    __syncthreads();
    float a = b1[t];
    #pragma unroll 4
    for (int k = 0; k < DD; k++) a = fmaf(g[k], W1[k * DD + t], a);
    float h = fmaxf(a, 0.f);
    float p = h * W2[t];
    p = wave_sum(p);
    int lane = t & 63, w = t >> 6;
    if (lane == 0) red[w] = p;
    __syncthreads();
    if (t == 0) out[gi] = red[0] + red[1] + b2[0];
}

extern "C" void kernel_launch(void* const* d_in, const int* in_sizes, int n_in,
                              void* d_out, int out_size, void* d_ws, size_t ws_size,
                              hipStream_t stream) {
    const float* x    = (const float*)d_in[0];
    const int*   ei   = (const int*)d_in[1];
    const int*   bat  = (const int*)d_in[3];
    const float* Wg1  = (const float*)d_in[4];
    const float* as1  = (const float*)d_in[5];
    const float* ad1  = (const float*)d_in[6];
    const float* bg1  = (const float*)d_in[7];
    const float* Wg2  = (const float*)d_in[8];
    const float* as2  = (const float*)d_in[9];
    const float* ad2  = (const float*)d_in[10];
    const float* bg2  = (const float*)d_in[11];
    const float* Wl1  = (const float*)d_in[12];
    const float* bl1  = (const float*)d_in[13];
    const float* Wl2  = (const float*)d_in[14];
    const float* bl2  = (const float*)d_in[15];
    const int* src = ei;
    const int* dst = ei + NE;

    char* ws = (char*)d_ws;
    __half* Hh   = (__half*)(ws);                        // 12,800,000
    __half* Yh   = (__half*)(ws + 12800000);             // 12,800,000
    float* asrc  = (float*)(ws + 25600000);              // 200,000
    float* adst  = (float*)(ws + 25800000);              // 200,000
    int*   deg   = (int*)  (ws + 26000000);              // 200,192 (50048 nodes)
    unsigned short* adj = (unsigned short*)(ws + 26200192); // 6,406,144 (50048*64*2)
    __half* Wt1  = (__half*)(ws + 32606336);             // 32,768
    __half* Wt2  = (__half*)(ws + 32639104);             // 32,768
    unsigned* bins = (unsigned*)(ws + 32671872);         // 4,804,608 (391*3072*4)
    int2*  opair = (int2*) (ws + 37476480);              // 524,288
    int*   bcnt  = (int*)  (ws + 38000768);              // 2,048 (zero region start)
    int*   ocnt  = (int*)  (ws + 38002816);              // 256
    float* gsum  = (float*)(ws + 38003072);              // 32,768
    int*   gcnt  = (int*)  (ws + 38035840);              // 256  (zero region end)

    // zero: bcnt + ocnt + gsum + gcnt = 35,328 bytes
    hipMemsetAsync(bcnt, 0, 35328, stream);

    k_wprep<<<8, 256, 0, stream>>>(Wg1, Wg2, Wt1, Wt2);
    // layer-1 MFMA gemm (1/3 blocks) interleaved with bin-scatter (2/3)
    k_mm1_sc<<<3 * MM_BLOCKS, 256, 0, stream>>>(
        x, Wt1, as1, ad1, Hh, asrc, adst, src, dst, bcnt, bins, opair, ocnt);
    k_bbuild<<<NBUK, 256, 0, stream>>>(bcnt, bins, adj, deg, opair, ocnt);
    k_aggr<4, false><<<NN / 4, 256, 0, stream>>>(
        Hh, asrc, adst, deg, adj, opair, ocnt, bg1, bat, nullptr, nullptr, Yh);
    k_mm2<<<MM_BLOCKS, 256, 0, stream>>>(Yh, Wt2, as2, ad2, Hh, asrc, adst);
    k_aggr<8, true><<<NN / 8, 512, 0, stream>>>(
        Hh, asrc, adst, deg, adj, opair, ocnt, bg2, bat, gsum, gcnt, nullptr);
    k_mlp<<<NG, 128, 0, stream>>>(gsum, gcnt, Wl1, bl1, Wl2, bl2, (float*)d_out);
}

// Round 13
// 245.567 us; speedup vs baseline: 2.0908x; 2.0908x over previous
//
#include <hip/hip_runtime.h>
#include <hip/hip_fp16.h>
#include <math.h>

#define NN 50000
#define NE 800000
#define DD 128
#define NG 64
#define NEG 0.2f
#define KMAX 64                  // fixed-width adjacency slots per node
#define OCAP 65536               // overflow pair capacity (never hit: deg<=~40)
#define NBUK 391                 // dst buckets of 128 nodes
#define BCAP 3072                // bin capacity (mean 2048, 22-sigma headroom)
#define MM_BLOCKS 391            // ceil(50000/128)
#define SCAT_BLOCKS 98           // ceil(200000 int4-groups / 2048)

typedef _Float16 half8 __attribute__((ext_vector_type(8)));
typedef float f32x4 __attribute__((ext_vector_type(4)));

__device__ __forceinline__ float leaky(float x) { return x >= 0.f ? x : NEG * x; }

__device__ __forceinline__ float wave_sum(float v) {
    #pragma unroll
    for (int o = 32; o; o >>= 1) v += __shfl_xor(v, o, 64);
    return v;
}

// ---------------- W prep: transpose + fp16 cast, Wt[col][k] ----------------
__launch_bounds__(256)
__global__ void k_wprep(const float* __restrict__ W1, const float* __restrict__ W2,
                        __half* __restrict__ Wt1, __half* __restrict__ Wt2) {
    int blk = blockIdx.x;                  // 0..7: 4 per W
    const float* W = (blk < 4) ? W1 : W2;
    __half* Wt = (blk < 4) ? Wt1 : Wt2;
    int t = threadIdx.x;
    int col = (blk & 3) * 32 + (t & 31);
    int kh = t >> 5;                       // 0..7
    #pragma unroll
    for (int kk = 0; kk < 16; kk++) {
        int k = kh * 16 + kk;
        Wt[col * DD + k] = __float2half(W[k * DD + col]);
    }
}

// ---------------- MFMA fp16 GEMM body ----------------
// 128 rows/block, 4 waves x (32 rows x 128 cols). mfma_f32_16x16x32_f16.
// Verified numerically on-device R11 (absmax 1.5e-5). smem: 64 KB overlay
// passed in by the caller (shared with the scatter role in the fused kernel).
template<bool SRC16>
__device__ __forceinline__ void mm_body(
        int gblk, const void* __restrict__ Xsrc, const __half* __restrict__ Wt,
        const float* __restrict__ att_s, const float* __restrict__ att_d,
        __half* __restrict__ Hh, float* __restrict__ asrc, float* __restrict__ adst,
        unsigned char* smem) {
    unsigned char* XsB = smem;                     // 32 KB
    unsigned char* WtB = smem + 32768;             // 32 KB
    int tid = threadIdx.x;
    int rowbase = gblk * 128;
    #pragma unroll
    for (int i = 0; i < 8; i++) {                  // stage A tile (fp16, swizzled)
        int slot = tid + i * 256;
        int rl = slot >> 4, c16 = slot & 15;
        int gr = rowbase + rl; if (gr > NN - 1) gr = NN - 1;
        uint4 v;
        if constexpr (SRC16) {
            v = ((const uint4*)Xsrc)[gr * 16 + c16];
        } else {
            const float4* Xf = (const float4*)Xsrc;
            float4 f0 = Xf[(size_t)gr * 32 + c16 * 2];
            float4 f1 = Xf[(size_t)gr * 32 + c16 * 2 + 1];
            __half2* o = (__half2*)&v;
            o[0] = __floats2half2_rn(f0.x, f0.y);
            o[1] = __floats2half2_rn(f0.z, f0.w);
            o[2] = __floats2half2_rn(f1.x, f1.y);
            o[3] = __floats2half2_rn(f1.z, f1.w);
        }
        *(uint4*)(XsB + rl * 256 + ((c16 * 16) ^ ((rl & 7) << 4))) = v;
    }
    #pragma unroll
    for (int i = 0; i < 8; i++) {                  // stage Wt (swizzled)
        int slot = tid + i * 256;
        int col = slot >> 4, c16 = slot & 15;
        uint4 v = ((const uint4*)Wt)[col * 16 + c16];
        *(uint4*)(WtB + col * 256 + ((c16 * 16) ^ ((col & 7) << 4))) = v;
    }
    __syncthreads();

    int l = tid & 63, wv = tid >> 6;
    f32x4 acc0[8], acc1[8];
    #pragma unroll
    for (int n = 0; n < 8; n++) { acc0[n] = (f32x4){0.f,0.f,0.f,0.f}; acc1[n] = (f32x4){0.f,0.f,0.f,0.f}; }
    int row0 = wv * 32 + (l & 15);
    int row1 = row0 + 16;
    int sw = (l & 7) << 4;                         // == (row&7)<<4 == (col&7)<<4
    #pragma unroll
    for (int ks = 0; ks < 4; ks++) {
        int kb = ks * 64 + ((l >> 4) << 4);        // byte offset of this lane's 8 fp16
        half8 a0 = *(const half8*)(XsB + row0 * 256 + (kb ^ sw));
        half8 a1 = *(const half8*)(XsB + row1 * 256 + (kb ^ sw));
        #pragma unroll
        for (int n = 0; n < 8; n++) {
            int col = n * 16 + (l & 15);
            half8 b = *(const half8*)(WtB + col * 256 + (kb ^ sw));
            acc0[n] = __builtin_amdgcn_mfma_f32_16x16x32_f16(a0, b, acc0[n], 0, 0, 0);
            acc1[n] = __builtin_amdgcn_mfma_f32_16x16x32_f16(a1, b, acc1[n], 0, 0, 0);
        }
    }
    // epilogue: attention dots from f32 acc (row-reduce over the 16 col-lanes)
    float asv[8], adv[8];
    #pragma unroll
    for (int n = 0; n < 8; n++) {
        asv[n] = att_s[n * 16 + (l & 15)];
        adv[n] = att_d[n * 16 + (l & 15)];
    }
    #pragma unroll
    for (int a = 0; a < 2; a++) {
        #pragma unroll
        for (int r = 0; r < 4; r++) {
            float ps = 0.f, pd = 0.f;
            #pragma unroll
            for (int n = 0; n < 8; n++) {
                float c = a ? acc1[n][r] : acc0[n][r];
                ps = fmaf(c, asv[n], ps);
                pd = fmaf(c, adv[n], pd);
            }
            #pragma unroll
            for (int off = 1; off < 16; off <<= 1) {
                ps += __shfl_xor(ps, off, 64);
                pd += __shfl_xor(pd, off, 64);
            }
            int gr = rowbase + wv * 32 + a * 16 + ((l >> 4) << 2) + r;
            if ((l & 15) == 0 && gr < NN) { asrc[gr] = ps; adst[gr] = pd; }
        }
    }
    // bounce acc -> LDS (linear fp16 [row][col]) -> coalesced 16B global stores
    #pragma unroll
    for (int a = 0; a < 2; a++) {
        #pragma unroll
        for (int n = 0; n < 8; n++) {
            #pragma unroll
            for (int r = 0; r < 4; r++) {
                int rl = wv * 32 + a * 16 + ((l >> 4) << 2) + r;
                float c = a ? acc1[n][r] : acc0[n][r];
                *(__half*)(XsB + rl * 256 + (n * 16 + (l & 15)) * 2) = __float2half(c);
            }
        }
    }
    __syncthreads();
    #pragma unroll
    for (int i = 0; i < 8; i++) {
        int slot = i * 64 + l;
        int rl = wv * 32 + (slot >> 4), c16 = slot & 15;
        int gr = rowbase + rl;
        if (gr < NN)
            ((uint4*)Hh)[(size_t)gr * 16 + c16] = *(const uint4*)(XsB + rl * 256 + c16 * 16);
    }
}

// bin-scatter, per-block LDS-staged reservation (R11 post-mortem fix):
// (a) per-bucket counts in LDS; (b) ONE global atomicAdd per non-empty bucket
// per block (38K total vs 800K, kills hot-spot serialization); (c) a block's
// edges land at consecutive bin addresses written in one phase on one XCD ->
// L2 merges them before writeback (kills per-store sector amplification).
__device__ __forceinline__ void scat_body(
        int sblk, const int* __restrict__ src, const int* __restrict__ dst,
        int* __restrict__ bcnt, unsigned* __restrict__ bins,
        int2* __restrict__ opair, int* __restrict__ ocnt, int* smem_i) {
    int* lcnt  = smem_i;           // [NBUK]
    int* lrank = smem_i + 512;     // [NBUK]
    int* gbase = smem_i + 1024;    // [NBUK]
    int tid = threadIdx.x;
    for (int b = tid; b < NBUK; b += 256) lcnt[b] = 0;
    __syncthreads();
    unsigned pk[32];
    int base = sblk * 2048;                        // int4-group index base
    #pragma unroll
    for (int j = 0; j < 8; j++) {
        int g = base + j * 256 + tid;
        bool valid = g < NE / 4;
        int gc = valid ? g : (NE / 4 - 1);         // clamp (load only)
        int4 s4 = ((const int4*)src)[gc];
        int4 d4 = ((const int4*)dst)[gc];
        if (valid) {
            pk[j * 4 + 0] = ((unsigned)d4.x << 16) | (unsigned)s4.x;
            pk[j * 4 + 1] = ((unsigned)d4.y << 16) | (unsigned)s4.y;
            pk[j * 4 + 2] = ((unsigned)d4.z << 16) | (unsigned)s4.z;
            pk[j * 4 + 3] = ((unsigned)d4.w << 16) | (unsigned)s4.w;
            atomicAdd(&lcnt[d4.x >> 7], 1);
            atomicAdd(&lcnt[d4.y >> 7], 1);
            atomicAdd(&lcnt[d4.z >> 7], 1);
            atomicAdd(&lcnt[d4.w >> 7], 1);
        } else {
            pk[j * 4 + 0] = 0xFFFFFFFFu;           // sentinel (d<50000 => pk<0xC351xxxx)
            pk[j * 4 + 1] = 0xFFFFFFFFu;
            pk[j * 4 + 2] = 0xFFFFFFFFu;
            pk[j * 4 + 3] = 0xFFFFFFFFu;
        }
    }
    __syncthreads();
    for (int b = tid; b < NBUK; b += 256) {        // per-block segment reservation
        int c = lcnt[b];
        gbase[b] = c ? atomicAdd(&bcnt[b], c) : 0;
        lrank[b] = 0;
    }
    __syncthreads();
    #pragma unroll
    for (int i = 0; i < 32; i++) {
        unsigned p = pk[i];
        if (p != 0xFFFFFFFFu) {
            int b = p >> 23;                       // == dst >> 7
            int r = atomicAdd(&lrank[b], 1);
            int slot = gbase[b] + r;
            if (slot < BCAP) bins[b * BCAP + slot] = p;
            else { int o = atomicAdd(ocnt, 1); if (o < OCAP) opair[o] = make_int2((int)(p & 0xFFFFu), (int)(p >> 16)); }
        }
    }
}

// fused: layer-1 MFMA gemm (blocks [0,391)) || staged bin-scatter (blocks [391,489))
// 489 blocks x 64KB LDS = all co-resident on 256 CUs (2 blocks/CU) from t=0.
__launch_bounds__(256)
__global__ void k_mm1_sc(const float* __restrict__ X, const __half* __restrict__ Wt1,
                         const float* __restrict__ as1, const float* __restrict__ ad1,
                         __half* __restrict__ Hh, float* __restrict__ asrc,
                         float* __restrict__ adst,
                         const int* __restrict__ src, const int* __restrict__ dst,
                         int* __restrict__ bcnt, unsigned* __restrict__ bins,
                         int2* __restrict__ opair, int* __restrict__ ocnt) {
    __shared__ __align__(16) unsigned char smem[65536];
    if (blockIdx.x < MM_BLOCKS)
        mm_body<false>(blockIdx.x, X, Wt1, as1, ad1, Hh, asrc, adst, smem);
    else
        scat_body(blockIdx.x - MM_BLOCKS, src, dst, bcnt, bins, opair, ocnt, (int*)smem);
}

__launch_bounds__(256)
__global__ void k_mm2(const __half* __restrict__ Yh, const __half* __restrict__ Wt2,
                      const float* __restrict__ as2, const float* __restrict__ ad2,
                      __half* __restrict__ Hh, float* __restrict__ asrc,
                      float* __restrict__ adst) {
    __shared__ __align__(16) unsigned char smem[65536];
    mm_body<true>(blockIdx.x, Yh, Wt2, as2, ad2, Hh, asrc, adst, smem);
}

// pass 2 of build: per-128-node bucket, adjacency assembled in LDS, written coalesced
__launch_bounds__(256)
__global__ void k_bbuild(const int* __restrict__ bcnt, const unsigned* __restrict__ bins,
                         unsigned short* __restrict__ adj, int* __restrict__ deg,
                         int2* __restrict__ opair, int* __restrict__ ocnt) {
    __shared__ unsigned short ladj[128 * KMAX];    // 16 KB
    __shared__ int ldeg[128];
    int tid = threadIdx.x, b = blockIdx.x;
    if (tid < 128) ldeg[tid] = 0;
    __syncthreads();
    int n = bcnt[b]; if (n > BCAP) n = BCAP;
    for (int i = tid; i < n; i += 256) {
        unsigned p = bins[b * BCAP + i];
        int s = (int)(p & 0xFFFFu);
        int dl = (int)((p >> 16) & 127u);
        int r = atomicAdd(&ldeg[dl], 1);
        if (r < KMAX) ladj[dl * KMAX + r] = (unsigned short)s;
        else { int o = atomicAdd(ocnt, 1); if (o < OCAP) opair[o] = make_int2(s, (int)(p >> 16)); }
    }
    __syncthreads();
    const uint4* lsrc = (const uint4*)ladj;
    uint4* gdst = (uint4*)adj;
    #pragma unroll
    for (int i = 0; i < 4; i++)                    // 16 KB coalesced
        gdst[b * 1024 + tid + i * 256] = lsrc[tid + i * 256];
    int base = b * 128;
    if (tid < 128 && base + tid < NN) deg[base + tid] = ldeg[tid];
}

// ---------------- per-dst softmax + weighted aggregation ----------------
// One wave per dst node. Adjacency (ushort) + self-loop cached in regs via one
// coalesced load; per-edge exp in regs; (src,coef) via __shfl. Quarter-wave
// gather: 16 lanes/row (uint4 = 8 fp16), 16 edges (4 KB) in flight.
// POOL: fused global_mean_pool via LDS + per-run atomics. !POOL: Y out fp16.
template<int WPB, bool POOL>
__launch_bounds__(WPB * 64)
__global__ void k_aggr(const __half* __restrict__ Hh, const float* __restrict__ asrc,
                       const float* __restrict__ adst, const int* __restrict__ degp,
                       const unsigned short* __restrict__ adj,
                       const int2* __restrict__ opairs, const int* __restrict__ ocnt,
                       const float* __restrict__ bias, const int* __restrict__ batch,
                       float* __restrict__ gsum, int* __restrict__ gcnt,
                       __half* __restrict__ Yh) {
    int tid = threadIdx.x;
    int lane = tid & 63;
    int h = lane >> 4;                 // quarter id: edge slot within group of 4
    int fl = lane & 15;                // feature lane (8 fp16 each)
    int w = tid >> 6;
    int v = blockIdx.x * WPB + w;      // grid sized exactly: v < NN always
    float adv = adst[v];
    float e_self = __expf(leaky(asrc[v] + adv));
    int deg = degp[v];
    bool self_in_reg = (deg < KMAX);
    int lim = self_in_reg ? deg + 1 : KMAX;   // reg-cached slots (incl. self)

    int   sarr = v;
    float evl  = 0.f;
    if (lane < lim) {
        sarr = (lane < deg) ? (int)adj[(v << 6) + lane] : v;
        evl  = (lane < deg) ? __expf(leaky(asrc[sarr] + adv)) : e_self;
    }
    int oc = 0;
    float sloc = evl;
    if (deg > KMAX) {                              // overflow (never in practice)
        oc = ocnt[0];
        if (oc > OCAP) oc = OCAP;
        for (int j = lane; j < oc; j += 64) {
            int2 p = opairs[j];
            if (p.y == v) sloc += __expf(leaky(asrc[p.x] + adv));
        }
    }
    float ssum = wave_sum(sloc) + (self_in_reg ? 0.f : e_self);
    float inv = 1.f / (ssum + 1e-16f);

    const uint4* H4 = (const uint4*)Hh;            // row = 16 uint4 (256 B)
    float acc[8];
    #pragma unroll
    for (int t = 0; t < 8; t++) acc[t] = 0.f;

    for (int j = 0; j < lim; j += 16) {            // 16 edges per batch
        int su[4]; float cu[4];
        #pragma unroll
        for (int u = 0; u < 4; u++) {
            int idx = j + 4 * u + h;
            int im  = idx & 63;
            int   s = __shfl(sarr, im, 64);
            float p = __shfl(evl,  im, 64);
            bool ok = idx < lim;
            su[u] = ok ? s : v;
            cu[u] = ok ? p * inv : 0.f;
        }
        uint4 hv[4];
        #pragma unroll
        for (int u = 0; u < 4; u++)
            hv[u] = H4[(size_t)su[u] * 16 + fl];   // 4 independent 1KB wave-loads
        #pragma unroll
        for (int u = 0; u < 4; u++) {
            const __half2* p2 = (const __half2*)&hv[u];
            #pragma unroll
            for (int t = 0; t < 4; t++) {
                float2 f = __half22float2(p2[t]);
                acc[2 * t]     = fmaf(cu[u], f.x, acc[2 * t]);
                acc[2 * t + 1] = fmaf(cu[u], f.y, acc[2 * t + 1]);
            }
        }
    }
    if (!self_in_reg) {                            // deferred self + overflow
        {
            float c0 = (h == 0) ? e_self * inv : 0.f;
            uint4 hv = H4[(size_t)v * 16 + fl];
            const __half2* p2 = (const __half2*)&hv;
            #pragma unroll
            for (int t = 0; t < 4; t++) {
                float2 f = __half22float2(p2[t]);
                acc[2 * t]     = fmaf(c0, f.x, acc[2 * t]);
                acc[2 * t + 1] = fmaf(c0, f.y, acc[2 * t + 1]);
            }
        }
        for (int j = 0; j < oc; ++j) {             // expected 0 iterations
            int2 p = opairs[j];
            if (p.y != v) continue;
            float c = (h == 0) ? __expf(leaky(asrc[p.x] + adv)) * inv : 0.f;
            uint4 hv = H4[(size_t)p.x * 16 + fl];
            const __half2* p2 = (const __half2*)&hv;
            #pragma unroll
            for (int t = 0; t < 4; t++) {
                float2 f = __half22float2(p2[t]);
                acc[2 * t]     = fmaf(c, f.x, acc[2 * t]);
                acc[2 * t + 1] = fmaf(c, f.y, acc[2 * t + 1]);
            }
        }
    }
    #pragma unroll
    for (int t = 0; t < 8; t++) {                  // combine the 4 quarters
        acc[t] += __shfl_xor(acc[t], 16, 64);
        acc[t] += __shfl_xor(acc[t], 32, 64);
    }
    if constexpr (POOL) {
        __shared__ float sh[WPB][DD];
        __shared__ int sb[WPB];
        if (lane < 16) {
            const float4* B4 = (const float4*)bias;
            float4 b0 = B4[2 * fl], b1 = B4[2 * fl + 1];
            float4 o0, o1;
            o0.x = fmaxf(acc[0] + b0.x, 0.f);
            o0.y = fmaxf(acc[1] + b0.y, 0.f);
            o0.z = fmaxf(acc[2] + b0.z, 0.f);
            o0.w = fmaxf(acc[3] + b0.w, 0.f);
            o1.x = fmaxf(acc[4] + b1.x, 0.f);
            o1.y = fmaxf(acc[5] + b1.y, 0.f);
            o1.z = fmaxf(acc[6] + b1.z, 0.f);
            o1.w = fmaxf(acc[7] + b1.w, 0.f);
            *(float4*)&sh[w][8 * fl]     = o0;
            *(float4*)&sh[w][8 * fl + 4] = o1;
        }
        if (lane == 0) sb[w] = batch[v];
        __syncthreads();
        if (tid < DD) {                            // per-feature run flush
            int f = tid;
            float a = 0.f; int run = 0; int bcur = sb[0];
            #pragma unroll
            for (int r = 0; r < WPB; r++) {
                int b = sb[r];
                if (b != bcur) {
                    atomicAdd(&gsum[bcur * DD + f], a);
                    if (f == 0) atomicAdd(&gcnt[bcur], run);
                    a = 0.f; run = 0; bcur = b;
                }
                a += sh[r][f]; run++;
            }
            atomicAdd(&gsum[bcur * DD + f], a);
            if (f == 0) atomicAdd(&gcnt[bcur], run);
        }
    } else {
        if (lane < 16) {
            const float4* B4 = (const float4*)bias;
            float4 b0 = B4[2 * fl], b1 = B4[2 * fl + 1];
            float o[8];
            o[0] = fmaxf(acc[0] + b0.x, 0.f);
            o[1] = fmaxf(acc[1] + b0.y, 0.f);
            o[2] = fmaxf(acc[2] + b0.z, 0.f);
            o[3] = fmaxf(acc[3] + b0.w, 0.f);
            o[4] = fmaxf(acc[4] + b1.x, 0.f);
            o[5] = fmaxf(acc[5] + b1.y, 0.f);
            o[6] = fmaxf(acc[6] + b1.z, 0.f);
            o[7] = fmaxf(acc[7] + b1.w, 0.f);
            uint4 pk;
            __half2* p2 = (__half2*)&pk;
            p2[0] = __floats2half2_rn(o[0], o[1]);
            p2[1] = __floats2half2_rn(o[2], o[3]);
            p2[2] = __floats2half2_rn(o[4], o[5]);
            p2[3] = __floats2half2_rn(o[6], o[7]);
            ((uint4*)Yh)[(size_t)v * 16 + fl] = pk;
        }
    }
}

// ---------------- final MLP: relu(g@W1+b1)@W2+b2 ----------------
__launch_bounds__(128)
__global__ void k_mlp(const float* __restrict__ gsum, const int* __restrict__ gcnt,
                      const float* __restrict__ W1, const float* __restrict__ b1,
                      const float* __restrict__ W2, const float* __restrict__ b2,
                      float* __restrict__ out) {
    __shared__ float g[DD];
    __shared__ float red[2];
    int gi = blockIdx.x, t = threadIdx.x;
    float cnt = fmaxf((float)gcnt[gi], 1.f);
    g[t] = gsum[gi * DD + t] / cnt;
    __syncthreads();
    float a = b1[t];
    #pragma unroll 4
    for (int k = 0; k < DD; k++) a = fmaf(g[k], W1[k * DD + t], a);
    float h = fmaxf(a, 0.f);
    float p = h * W2[t];
    p = wave_sum(p);
    int lane = t & 63, w = t >> 6;
    if (lane == 0) red[w] = p;
    __syncthreads();
    if (t == 0) out[gi] = red[0] + red[1] + b2[0];
}

extern "C" void kernel_launch(void* const* d_in, const int* in_sizes, int n_in,
                              void* d_out, int out_size, void* d_ws, size_t ws_size,
                              hipStream_t stream) {
    const float* x    = (const float*)d_in[0];
    const int*   ei   = (const int*)d_in[1];
    const int*   bat  = (const int*)d_in[3];
    const float* Wg1  = (const float*)d_in[4];
    const float* as1  = (const float*)d_in[5];
    const float* ad1  = (const float*)d_in[6];
    const float* bg1  = (const float*)d_in[7];
    const float* Wg2  = (const float*)d_in[8];
    const float* as2  = (const float*)d_in[9];
    const float* ad2  = (const float*)d_in[10];
    const float* bg2  = (const float*)d_in[11];
    const float* Wl1  = (const float*)d_in[12];
    const float* bl1  = (const float*)d_in[13];
    const float* Wl2  = (const float*)d_in[14];
    const float* bl2  = (const float*)d_in[15];
    const int* src = ei;
    const int* dst = ei + NE;

    char* ws = (char*)d_ws;
    __half* Hh   = (__half*)(ws);                        // 12,800,000
    __half* Yh   = (__half*)(ws + 12800000);             // 12,800,000
    float* asrc  = (float*)(ws + 25600000);              // 200,000
    float* adst  = (float*)(ws + 25800000);              // 200,000
    int*   deg   = (int*)  (ws + 26000000);              // 200,192 (50048 nodes)
    unsigned short* adj = (unsigned short*)(ws + 26200192); // 6,406,144 (50048*64*2)
    __half* Wt1  = (__half*)(ws + 32606336);             // 32,768
    __half* Wt2  = (__half*)(ws + 32639104);             // 32,768
    unsigned* bins = (unsigned*)(ws + 32671872);         // 4,804,608 (391*3072*4)
    int2*  opair = (int2*) (ws + 37476480);              // 524,288
    int*   bcnt  = (int*)  (ws + 38000768);              // 2,048 (zero region start)
    int*   ocnt  = (int*)  (ws + 38002816);              // 256
    float* gsum  = (float*)(ws + 38003072);              // 32,768
    int*   gcnt  = (int*)  (ws + 38035840);              // 256  (zero region end)

    // zero: bcnt + ocnt + gsum + gcnt = 35,328 bytes
    hipMemsetAsync(bcnt, 0, 35328, stream);

    k_wprep<<<8, 256, 0, stream>>>(Wg1, Wg2, Wt1, Wt2);
    // layer-1 MFMA gemm || LDS-staged bin-scatter (all 489 blocks co-resident)
    k_mm1_sc<<<MM_BLOCKS + SCAT_BLOCKS, 256, 0, stream>>>(
        x, Wt1, as1, ad1, Hh, asrc, adst, src, dst, bcnt, bins, opair, ocnt);
    k_bbuild<<<NBUK, 256, 0, stream>>>(bcnt, bins, adj, deg, opair, ocnt);
    k_aggr<4, false><<<NN / 4, 256, 0, stream>>>(
        Hh, asrc, adst, deg, adj, opair, ocnt, bg1, bat, nullptr, nullptr, Yh);
    k_mm2<<<MM_BLOCKS, 256, 0, stream>>>(Yh, Wt2, as2, ad2, Hh, asrc, adst);
    k_aggr<8, true><<<NN / 8, 512, 0, stream>>>(
        Hh, asrc, adst, deg, adj, opair, ocnt, bg2, bat, gsum, gcnt, nullptr);
    k_mlp<<<NG, 128, 0, stream>>>(gsum, gcnt, Wl1, bl1, Wl2, bl2, (float*)d_out);
}